// Round 2
// baseline (968.275 us; speedup 1.0000x reference)
//
#include <hip/hip_runtime.h>
#include <hip/hip_bf16.h>
#include <math.h>

#define H 128
#define XS 300
#define NCLS 5

#define BM 64
#define BN 64
#define BK 16
#define G 4   // parents per block in level kernel

// ---------------------------------------------------------------------------
// mask conversion with dtype auto-detect (bool-bytes vs int32)
// ---------------------------------------------------------------------------
__global__ void mask_conv_kernel(const void* __restrict__ mask_raw,
                                 float* __restrict__ m, int n) {
    // detect storage: if any of the first 16 u32 words > 1, data is byte-packed bools
    const unsigned int* w = (const unsigned int*)mask_raw;
    bool is_bytes = false;
#pragma unroll
    for (int i = 0; i < 16; i++) is_bytes |= (w[i] > 1u);
    int idx = blockIdx.x * blockDim.x + threadIdx.x;
    if (idx >= n) return;
    float mv;
    if (is_bytes) {
        mv = ((const unsigned char*)mask_raw)[idx] ? 1.f : 0.f;
    } else {
        mv = ((const int*)mask_raw)[idx] ? 1.f : 0.f;
    }
    m[idx] = mv;
}

// ---------------------------------------------------------------------------
// Phase A: iou_in = m * (x @ W_iou + b_iou)   (n x 384)
//          f_in   = m * (x @ W_f   + b_f  )   (n x 128)
// one fused GEMM launch; grid.y 0..5 -> iou cols, 6..7 -> f cols
// ---------------------------------------------------------------------------
__global__ __launch_bounds__(256) void gemm_in_kernel(
    const float* __restrict__ x, const float* __restrict__ m,
    const float* __restrict__ W_iou, const float* __restrict__ b_iou,
    const float* __restrict__ W_f, const float* __restrict__ b_f,
    float* __restrict__ iou_in, float* __restrict__ f_in, int n)
{
    __shared__ float As[BK][BM + 4];
    __shared__ float Bs[BK][BN];

    int bm = blockIdx.x;
    int bn = blockIdx.y;
    const float* W; const float* bias; float* out; int ldw; int col0;
    if (bn < 6) { W = W_iou; bias = b_iou; out = iou_in; ldw = 384; col0 = bn * 64; }
    else        { W = W_f;   bias = b_f;   out = f_in;   ldw = 128; col0 = (bn - 6) * 64; }

    int t  = threadIdx.x;
    int tx = t & 15, ty = t >> 4;
    int m0 = bm * BM;

    float acc[4][4];
#pragma unroll
    for (int i = 0; i < 4; i++)
#pragma unroll
        for (int j = 0; j < 4; j++) acc[i][j] = 0.f;

    for (int k0 = 0; k0 < XS; k0 += BK) {
        {   // load A tile (64 rows x 16 k), transposed store
            int k = t & 15, r = t >> 4;
#pragma unroll
            for (int i = 0; i < 4; i++) {
                int row = m0 + r + i * 16;
                int kk  = k0 + k;
                As[k][r + i * 16] =
                    (row < n && kk < XS) ? x[(size_t)row * XS + kk] : 0.f;
            }
        }
        {   // load B tile (16 k x 64 cols)
            int cc = t & 63, kk = t >> 6;
#pragma unroll
            for (int i = 0; i < 4; i++) {
                int krow = k0 + kk + i * 4;
                Bs[kk + i * 4][cc] =
                    (krow < XS) ? W[(size_t)krow * ldw + col0 + cc] : 0.f;
            }
        }
        __syncthreads();
#pragma unroll
        for (int kk = 0; kk < BK; kk++) {
            float a[4], b[4];
#pragma unroll
            for (int i = 0; i < 4; i++) a[i] = As[kk][ty * 4 + i];
#pragma unroll
            for (int j = 0; j < 4; j++) b[j] = Bs[kk][tx * 4 + j];
#pragma unroll
            for (int i = 0; i < 4; i++)
#pragma unroll
                for (int j = 0; j < 4; j++) acc[i][j] = fmaf(a[i], b[j], acc[i][j]);
        }
        __syncthreads();
    }

#pragma unroll
    for (int i = 0; i < 4; i++) {
        int row = m0 + ty * 4 + i;
        if (row >= n) continue;
        float mv = m[row];
#pragma unroll
        for (int j = 0; j < 4; j++) {
            int col = col0 + tx * 4 + j;
            out[(size_t)row * ldw + col] = mv * (acc[i][j] + bias[col]);
        }
    }
}

// ---------------------------------------------------------------------------
// Leaves (level 10): c = i*u, h = o*tanh(c), gates from iou_in only
// ---------------------------------------------------------------------------
__global__ void leaf_kernel(const float* __restrict__ iou_in,
                            float* __restrict__ h, float* __restrict__ c,
                            int start, int count)
{
    int idx = blockIdx.x * blockDim.x + threadIdx.x;
    int total = count * H;
    if (idx >= total) return;
    int v = start + idx / H;
    int d = idx & (H - 1);
    const float* row = iou_in + (size_t)v * 384;
    float iv = row[d], ov = row[128 + d], uv = row[256 + d];
    float ig = 1.f / (1.f + __expf(-iv));
    float og = 1.f / (1.f + __expf(-ov));
    float ug = tanhf(uv);
    float cv = ig * ug;
    float hv = og * tanhf(cv);
    c[(size_t)v * H + d] = cv;
    h[(size_t)v * H + d] = hv;
}

// ---------------------------------------------------------------------------
// One internal level: per parent p (global v = P0+p), children 3v+1..3v+3
//   f_k   = sigmoid(f_in[v] + h[ch_k] @ U_f)     (parent's f_in!)
//   fcs   = sum f_k * c[ch_k];   hs = sum h[ch_k]
//   iou   = iou_in[v] + hs @ U_iou -> gates -> c[v], h[v]
// G parents per block, 128 threads (thread = hidden dim d)
// ---------------------------------------------------------------------------
__global__ __launch_bounds__(128) void level_kernel(
    const float* __restrict__ iou_in, const float* __restrict__ f_in,
    const float* __restrict__ U_iou, const float* __restrict__ U_f,
    float* __restrict__ h, float* __restrict__ c,
    int P0, int NP)
{
    __shared__ float ch_h[3 * G][H];
    __shared__ float hs[G][H];

    int d  = threadIdx.x;            // 0..127
    int p0 = blockIdx.x * G;         // parent offset within level
    int C0 = 3 * P0 + 1;             // first child global index

    int nch = 3 * (NP - p0);         // valid children in this block
    if (nch > 3 * G) nch = 3 * G;

    for (int cc = 0; cc < 3 * G; cc++) {
        int child = C0 + 3 * p0 + cc;
        ch_h[cc][d] = (cc < nch) ? h[(size_t)child * H + d] : 0.f;
    }
    __syncthreads();

    // U_f matvecs: acc[cc] = sum_k ch_h[cc][k] * U_f[k][d]
    float acc[3 * G];
#pragma unroll
    for (int cc = 0; cc < 3 * G; cc++) acc[cc] = 0.f;
    for (int k = 0; k < H; k += 4) {
        float u0 = U_f[(size_t)(k + 0) * H + d];
        float u1 = U_f[(size_t)(k + 1) * H + d];
        float u2 = U_f[(size_t)(k + 2) * H + d];
        float u3 = U_f[(size_t)(k + 3) * H + d];
#pragma unroll
        for (int cc = 0; cc < 3 * G; cc++) {
            float4 hv = *reinterpret_cast<const float4*>(&ch_h[cc][k]);
            acc[cc] = fmaf(hv.x, u0, acc[cc]);
            acc[cc] = fmaf(hv.y, u1, acc[cc]);
            acc[cc] = fmaf(hv.z, u2, acc[cc]);
            acc[cc] = fmaf(hv.w, u3, acc[cc]);
        }
    }

    // forget gates, fc sums, h sums
    float fcs[G];
#pragma unroll
    for (int g = 0; g < G; g++) {
        int p = p0 + g;
        bool valid = (p < NP);
        float fpre = valid ? f_in[(size_t)(P0 + p) * H + d] : 0.f;
        float s = 0.f, hsum = 0.f;
#pragma unroll
        for (int j = 0; j < 3; j++) {
            int cc = 3 * g + j;
            float fg = 1.f / (1.f + __expf(-(fpre + acc[cc])));
            float cv = valid ? c[(size_t)(C0 + 3 * p + j) * H + d] : 0.f;
            s    += fg * cv;
            hsum += ch_h[cc][d];
        }
        fcs[g]   = s;
        hs[g][d] = hsum;
    }
    __syncthreads();

    // U_iou matvec: columns d (i), 128+d (o), 256+d (u) per parent
    float a0[G], a1[G], a2[G];
#pragma unroll
    for (int g = 0; g < G; g++) { a0[g] = 0.f; a1[g] = 0.f; a2[g] = 0.f; }
    for (int k = 0; k < H; k++) {
        float u0 = U_iou[(size_t)k * 384 + d];
        float u1 = U_iou[(size_t)k * 384 + 128 + d];
        float u2 = U_iou[(size_t)k * 384 + 256 + d];
#pragma unroll
        for (int g = 0; g < G; g++) {
            float hv = hs[g][k];
            a0[g] = fmaf(hv, u0, a0[g]);
            a1[g] = fmaf(hv, u1, a1[g]);
            a2[g] = fmaf(hv, u2, a2[g]);
        }
    }

#pragma unroll
    for (int g = 0; g < G; g++) {
        int p = p0 + g;
        if (p >= NP) continue;
        int v = P0 + p;
        const float* irow = iou_in + (size_t)v * 384;
        float ig = 1.f / (1.f + __expf(-(irow[d]       + a0[g])));
        float og = 1.f / (1.f + __expf(-(irow[128 + d] + a1[g])));
        float ug = tanhf(irow[256 + d] + a2[g]);
        float cv = ig * ug + fcs[g];
        float hv = og * tanhf(cv);
        c[(size_t)v * H + d] = cv;
        h[(size_t)v * H + d] = hv;
    }
}

// ---------------------------------------------------------------------------
// Output head: out = h @ W_out + b_out   (n x 5), one wave per node
// ---------------------------------------------------------------------------
__global__ __launch_bounds__(256) void out_kernel(
    const float* __restrict__ h, const float* __restrict__ W_out,
    const float* __restrict__ b_out, float* __restrict__ out, int n)
{
    int wave = (blockIdx.x * blockDim.x + threadIdx.x) >> 6;
    int lane = threadIdx.x & 63;
    if (wave >= n) return;
    const float* hr = h + (size_t)wave * H;
    float h0 = hr[lane], h1 = hr[lane + 64];
    float a[NCLS];
#pragma unroll
    for (int j = 0; j < NCLS; j++)
        a[j] = h0 * W_out[lane * NCLS + j] + h1 * W_out[(lane + 64) * NCLS + j];
#pragma unroll
    for (int off = 32; off > 0; off >>= 1)
#pragma unroll
        for (int j = 0; j < NCLS; j++)
            a[j] += __shfl_down(a[j], off, 64);
    if (lane == 0) {
#pragma unroll
        for (int j = 0; j < NCLS; j++)
            out[(size_t)wave * NCLS + j] = a[j] + b_out[j];
    }
}

// ---------------------------------------------------------------------------
extern "C" void kernel_launch(void* const* d_in, const int* in_sizes, int n_in,
                              void* d_out, int out_size, void* d_ws, size_t ws_size,
                              hipStream_t stream) {
    const float* x     = (const float*)d_in[0];
    const void*  mask  = d_in[1];
    const float* W_iou = (const float*)d_in[2];
    const float* b_iou = (const float*)d_in[3];
    const float* W_f   = (const float*)d_in[4];
    const float* b_f   = (const float*)d_in[5];
    const float* U_iou = (const float*)d_in[6];
    const float* U_f   = (const float*)d_in[7];
    const float* W_out = (const float*)d_in[8];
    const float* b_out = (const float*)d_in[9];
    float* out = (float*)d_out;

    int n = in_sizes[1];   // 88573

    float* ws     = (float*)d_ws;
    float* iou_in = ws;                              // n*384
    float* f_in   = iou_in + (size_t)n * 384;        // n*128
    float* hbuf   = f_in   + (size_t)n * 128;        // n*128
    float* cbuf   = hbuf   + (size_t)n * 128;        // n*128
    float* mbuf   = cbuf   + (size_t)n * 128;        // n

    // 3^l table
    int pow3[11];
    pow3[0] = 1;
    for (int i = 1; i < 11; i++) pow3[i] = pow3[i - 1] * 3;

    // 0. mask -> float
    mask_conv_kernel<<<(n + 255) / 256, 256, 0, stream>>>(mask, mbuf, n);

    // 1. input GEMMs (fused iou_in + f_in)
    dim3 gA((n + BM - 1) / BM, 8);
    gemm_in_kernel<<<gA, 256, 0, stream>>>(x, mbuf, W_iou, b_iou, W_f, b_f,
                                           iou_in, f_in, n);

    // 2. leaves (level 10)
    {
        int start = (pow3[10] - 1) / 2;   // 29524
        int count = pow3[10];             // 59049
        int total = count * H;
        leaf_kernel<<<(total + 255) / 256, 256, 0, stream>>>(iou_in, hbuf, cbuf,
                                                             start, count);
    }

    // 3. internal levels 9..0
    for (int lvl = 9; lvl >= 0; --lvl) {
        int NP = pow3[lvl];
        int P0 = (pow3[lvl] - 1) / 2;
        int grid = (NP + G - 1) / G;
        level_kernel<<<grid, 128, 0, stream>>>(iou_in, f_in, U_iou, U_f,
                                               hbuf, cbuf, P0, NP);
    }

    // 4. output head
    {
        int blocks = (n + 3) / 4;   // 4 waves (nodes) per 256-thread block
        out_kernel<<<blocks, 256, 0, stream>>>(hbuf, W_out, b_out, out, n);
    }
}

// Round 3
// 681.309 us; speedup vs baseline: 1.4212x; 1.4212x over previous
//
#include <hip/hip_runtime.h>
#include <hip/hip_bf16.h>
#include <math.h>

#define H 128
#define XS 300
#define NCLS 5
#define KPAD 320
#define G 4   // parents per block in level kernel

typedef __attribute__((ext_vector_type(8))) short short8;
typedef __attribute__((ext_vector_type(4))) float f32x4;

static __device__ inline unsigned short f2bf(float f) {
    __hip_bfloat16 h = __float2bfloat16(f);
    return *reinterpret_cast<unsigned short*>(&h);
}

// ---------------------------------------------------------------------------
// mask conversion with dtype auto-detect (bool-bytes vs int32)
// ---------------------------------------------------------------------------
__global__ void mask_conv_kernel(const void* __restrict__ mask_raw,
                                 float* __restrict__ m, int n) {
    const unsigned int* w = (const unsigned int*)mask_raw;
    bool is_bytes = false;
#pragma unroll
    for (int i = 0; i < 16; i++) is_bytes |= (w[i] > 1u);
    int idx = blockIdx.x * blockDim.x + threadIdx.x;
    if (idx >= n) return;
    float mv;
    if (is_bytes) mv = ((const unsigned char*)mask_raw)[idx] ? 1.f : 0.f;
    else          mv = ((const int*)mask_raw)[idx] ? 1.f : 0.f;
    m[idx] = mv;
}

// ---------------------------------------------------------------------------
// W -> transposed bf16: Wb_t[c][k], c in [0,512) (384 iou cols then 128 f),
// k in [0,320) zero-padded past 300
// ---------------------------------------------------------------------------
__global__ void wconv_kernel(const float* __restrict__ W_iou,
                             const float* __restrict__ W_f,
                             unsigned short* __restrict__ Wb_t) {
    int c = blockIdx.x;     // 0..511
    int k = threadIdx.x;    // 0..319
    float v = 0.f;
    if (k < XS) v = (c < 384) ? W_iou[(size_t)k * 384 + c]
                              : W_f[(size_t)k * 128 + (c - 384)];
    Wb_t[(size_t)c * KPAD + k] = f2bf(v);
}

// ---------------------------------------------------------------------------
// Phase A via MFMA: C[n x 512] = x[n x 300] @ [W_iou | W_f], bias+mask fused.
// Block: 128 rows x 128 cols, 4 waves (2x2), K-step 64 (2 mfma k-subtiles).
// A: fp32 global -> cvt bf16 -> LDS.  B: pre-converted Wb_t rows -> LDS.
// LDS stride 72 shorts (144B) keeps ds_read_b128 bank-balanced.
// ---------------------------------------------------------------------------
__global__ __launch_bounds__(256) void gemm_in_mfma(
    const float* __restrict__ x, const float* __restrict__ m,
    const unsigned short* __restrict__ Wb_t,
    const float* __restrict__ b_iou, const float* __restrict__ b_f,
    float* __restrict__ iou_in, float* __restrict__ f_in, int n)
{
    __shared__ __align__(16) unsigned short Asld[128][72];
    __shared__ __align__(16) unsigned short Bsld[128][72];

    int bn = blockIdx.x;            // 0..3 col tile (fast-varying: L2 reuse of x)
    int bm = blockIdx.y;            // row tile
    int t    = threadIdx.x;
    int lane = t & 63;
    int wid  = t >> 6;
    int wr = wid >> 1, wc = wid & 1;

    int r0 = bm * 128;
    int c0 = bn * 128;

    f32x4 acc[4][4];
#pragma unroll
    for (int i = 0; i < 4; i++)
#pragma unroll
        for (int j = 0; j < 4; j++) acc[i][j] = (f32x4)0.f;

    for (int k0 = 0; k0 < KPAD; k0 += 64) {
        // --- stage A: 128 rows x 64 k. thread t: row (t>>4)+16p, k-quad (t&15)*4
        {
            int rr = t >> 4;
            int kq = (t & 15) << 2;
            int kg = k0 + kq;
#pragma unroll
            for (int p = 0; p < 8; p++) {
                int row  = r0 + rr + p * 16;
                int rowc = row < n ? row : n - 1;
                float4 v;
                if (kg + 4 <= XS) v = *(const float4*)&x[(size_t)rowc * XS + kg];
                else              v = make_float4(0.f, 0.f, 0.f, 0.f);
                ushort4 b4;
                b4.x = f2bf(v.x); b4.y = f2bf(v.y);
                b4.z = f2bf(v.z); b4.w = f2bf(v.w);
                *(ushort4*)&Asld[rr + p * 16][kq] = b4;
            }
        }
        // --- stage B: 128 cols x 64 k from Wb_t (already bf16, zero-padded)
        {
            int rr  = t >> 3;            // 0..31
            int kq8 = (t & 7) << 3;      // 0,8,...,56
#pragma unroll
            for (int p = 0; p < 4; p++) {
                int col = c0 + rr + p * 32;
                uint4 v = *(const uint4*)&Wb_t[(size_t)col * KPAD + k0 + kq8];
                *(uint4*)&Bsld[rr + p * 32][kq8] = v;
            }
        }
        __syncthreads();

#pragma unroll
        for (int ks = 0; ks < 2; ks++) {
            int kc = ks * 32 + (lane >> 4) * 8;
            short8 af[4], bf[4];
#pragma unroll
            for (int mi = 0; mi < 4; mi++)
                af[mi] = *(const short8*)&Asld[wr * 64 + mi * 16 + (lane & 15)][kc];
#pragma unroll
            for (int ni = 0; ni < 4; ni++)
                bf[ni] = *(const short8*)&Bsld[wc * 64 + ni * 16 + (lane & 15)][kc];
#pragma unroll
            for (int mi = 0; mi < 4; mi++)
#pragma unroll
                for (int ni = 0; ni < 4; ni++)
                    acc[mi][ni] = __builtin_amdgcn_mfma_f32_16x16x32_bf16(
                        af[mi], bf[ni], acc[mi][ni], 0, 0, 0);
        }
        __syncthreads();
    }

    // --- epilogue: bias + mask, write to iou_in (bn 0..2) or f_in (bn 3)
    const float* bias;
    float* outp;
    int ldw, colbase;
    if (bn < 3) { bias = b_iou; outp = iou_in; ldw = 384; colbase = bn * 128; }
    else        { bias = b_f;   outp = f_in;   ldw = 128; colbase = 0; }

    float bias_v[4];
#pragma unroll
    for (int ni = 0; ni < 4; ni++)
        bias_v[ni] = bias[colbase + wc * 64 + ni * 16 + (lane & 15)];

#pragma unroll
    for (int mi = 0; mi < 4; mi++) {
#pragma unroll
        for (int j = 0; j < 4; j++) {
            int row = r0 + wr * 64 + mi * 16 + (lane >> 4) * 4 + j;
            if (row >= n) continue;
            float mv = m[row];
#pragma unroll
            for (int ni = 0; ni < 4; ni++) {
                int col = colbase + wc * 64 + ni * 16 + (lane & 15);
                outp[(size_t)row * ldw + col] = mv * (acc[mi][ni][j] + bias_v[ni]);
            }
        }
    }
}

// ---------------------------------------------------------------------------
// Leaves (level 10): c = i*u, h = o*tanh(c); float4 vectorized
// ---------------------------------------------------------------------------
__global__ void leaf_kernel(const float* __restrict__ iou_in,
                            float* __restrict__ h, float* __restrict__ c,
                            int start, int count)
{
    int idx = blockIdx.x * blockDim.x + threadIdx.x;
    int total = count * 32;
    if (idx >= total) return;
    int v = start + (idx >> 5);
    int d = (idx & 31) * 4;
    const float* row = iou_in + (size_t)v * 384;
    float4 iv = *(const float4*)&row[d];
    float4 ov = *(const float4*)&row[128 + d];
    float4 uv = *(const float4*)&row[256 + d];
    float4 cv, hv;
    {
        float ig, og, ug;
        ig = 1.f / (1.f + __expf(-iv.x)); og = 1.f / (1.f + __expf(-ov.x)); ug = tanhf(uv.x);
        cv.x = ig * ug; hv.x = og * tanhf(cv.x);
        ig = 1.f / (1.f + __expf(-iv.y)); og = 1.f / (1.f + __expf(-ov.y)); ug = tanhf(uv.y);
        cv.y = ig * ug; hv.y = og * tanhf(cv.y);
        ig = 1.f / (1.f + __expf(-iv.z)); og = 1.f / (1.f + __expf(-ov.z)); ug = tanhf(uv.z);
        cv.z = ig * ug; hv.z = og * tanhf(cv.z);
        ig = 1.f / (1.f + __expf(-iv.w)); og = 1.f / (1.f + __expf(-ov.w)); ug = tanhf(uv.w);
        cv.w = ig * ug; hv.w = og * tanhf(cv.w);
    }
    *(float4*)&c[(size_t)v * H + d] = cv;
    *(float4*)&h[(size_t)v * H + d] = hv;
}

// ---------------------------------------------------------------------------
// One internal level (unchanged from round 0)
// ---------------------------------------------------------------------------
__global__ __launch_bounds__(128) void level_kernel(
    const float* __restrict__ iou_in, const float* __restrict__ f_in,
    const float* __restrict__ U_iou, const float* __restrict__ U_f,
    float* __restrict__ h, float* __restrict__ c,
    int P0, int NP)
{
    __shared__ float ch_h[3 * G][H];
    __shared__ float hs[G][H];

    int d  = threadIdx.x;
    int p0 = blockIdx.x * G;
    int C0 = 3 * P0 + 1;

    int nch = 3 * (NP - p0);
    if (nch > 3 * G) nch = 3 * G;

    for (int cc = 0; cc < 3 * G; cc++) {
        int child = C0 + 3 * p0 + cc;
        ch_h[cc][d] = (cc < nch) ? h[(size_t)child * H + d] : 0.f;
    }
    __syncthreads();

    float acc[3 * G];
#pragma unroll
    for (int cc = 0; cc < 3 * G; cc++) acc[cc] = 0.f;
    for (int k = 0; k < H; k += 4) {
        float u0 = U_f[(size_t)(k + 0) * H + d];
        float u1 = U_f[(size_t)(k + 1) * H + d];
        float u2 = U_f[(size_t)(k + 2) * H + d];
        float u3 = U_f[(size_t)(k + 3) * H + d];
#pragma unroll
        for (int cc = 0; cc < 3 * G; cc++) {
            float4 hv = *reinterpret_cast<const float4*>(&ch_h[cc][k]);
            acc[cc] = fmaf(hv.x, u0, acc[cc]);
            acc[cc] = fmaf(hv.y, u1, acc[cc]);
            acc[cc] = fmaf(hv.z, u2, acc[cc]);
            acc[cc] = fmaf(hv.w, u3, acc[cc]);
        }
    }

    float fcs[G];
#pragma unroll
    for (int g = 0; g < G; g++) {
        int p = p0 + g;
        bool valid = (p < NP);
        float fpre = valid ? f_in[(size_t)(P0 + p) * H + d] : 0.f;
        float s = 0.f, hsum = 0.f;
#pragma unroll
        for (int j = 0; j < 3; j++) {
            int cc = 3 * g + j;
            float fg = 1.f / (1.f + __expf(-(fpre + acc[cc])));
            float cvv = valid ? c[(size_t)(C0 + 3 * p + j) * H + d] : 0.f;
            s    += fg * cvv;
            hsum += ch_h[cc][d];
        }
        fcs[g]   = s;
        hs[g][d] = hsum;
    }
    __syncthreads();

    float a0[G], a1[G], a2[G];
#pragma unroll
    for (int g = 0; g < G; g++) { a0[g] = 0.f; a1[g] = 0.f; a2[g] = 0.f; }
    for (int k = 0; k < H; k++) {
        float u0 = U_iou[(size_t)k * 384 + d];
        float u1 = U_iou[(size_t)k * 384 + 128 + d];
        float u2 = U_iou[(size_t)k * 384 + 256 + d];
#pragma unroll
        for (int g = 0; g < G; g++) {
            float hv = hs[g][k];
            a0[g] = fmaf(hv, u0, a0[g]);
            a1[g] = fmaf(hv, u1, a1[g]);
            a2[g] = fmaf(hv, u2, a2[g]);
        }
    }

#pragma unroll
    for (int g = 0; g < G; g++) {
        int p = p0 + g;
        if (p >= NP) continue;
        int v = P0 + p;
        const float* irow = iou_in + (size_t)v * 384;
        float ig = 1.f / (1.f + __expf(-(irow[d]       + a0[g])));
        float og = 1.f / (1.f + __expf(-(irow[128 + d] + a1[g])));
        float ug = tanhf(irow[256 + d] + a2[g]);
        float cv = ig * ug + fcs[g];
        float hv = og * tanhf(cv);
        c[(size_t)v * H + d] = cv;
        h[(size_t)v * H + d] = hv;
    }
}

// ---------------------------------------------------------------------------
// Output head: out = h @ W_out + b_out (n x 5)
// ---------------------------------------------------------------------------
__global__ __launch_bounds__(256) void out_kernel(
    const float* __restrict__ h, const float* __restrict__ W_out,
    const float* __restrict__ b_out, float* __restrict__ out, int n)
{
    int wave = (blockIdx.x * blockDim.x + threadIdx.x) >> 6;
    int lane = threadIdx.x & 63;
    if (wave >= n) return;
    const float* hr = h + (size_t)wave * H;
    float h0 = hr[lane], h1 = hr[lane + 64];
    float a[NCLS];
#pragma unroll
    for (int j = 0; j < NCLS; j++)
        a[j] = h0 * W_out[lane * NCLS + j] + h1 * W_out[(lane + 64) * NCLS + j];
#pragma unroll
    for (int off = 32; off > 0; off >>= 1)
#pragma unroll
        for (int j = 0; j < NCLS; j++)
            a[j] += __shfl_down(a[j], off, 64);
    if (lane == 0) {
#pragma unroll
        for (int j = 0; j < NCLS; j++)
            out[(size_t)wave * NCLS + j] = a[j] + b_out[j];
    }
}

// ---------------------------------------------------------------------------
extern "C" void kernel_launch(void* const* d_in, const int* in_sizes, int n_in,
                              void* d_out, int out_size, void* d_ws, size_t ws_size,
                              hipStream_t stream) {
    const float* x     = (const float*)d_in[0];
    const void*  mask  = d_in[1];
    const float* W_iou = (const float*)d_in[2];
    const float* b_iou = (const float*)d_in[3];
    const float* W_f   = (const float*)d_in[4];
    const float* b_f   = (const float*)d_in[5];
    const float* U_iou = (const float*)d_in[6];
    const float* U_f   = (const float*)d_in[7];
    const float* W_out = (const float*)d_in[8];
    const float* b_out = (const float*)d_in[9];
    float* out = (float*)d_out;

    int n = in_sizes[1];   // 88573

    float* ws     = (float*)d_ws;
    float* iou_in = ws;                              // n*384
    float* f_in   = iou_in + (size_t)n * 384;        // n*128
    float* hbuf   = f_in   + (size_t)n * 128;        // n*128
    float* cbuf   = hbuf   + (size_t)n * 128;        // n*128
    float* mbuf   = cbuf   + (size_t)n * 128;        // n
    unsigned short* Wb_t = (unsigned short*)(mbuf + n);  // 512*320 bf16

    int pow3[11];
    pow3[0] = 1;
    for (int i = 1; i < 11; i++) pow3[i] = pow3[i - 1] * 3;

    // 0. mask -> float ; W -> bf16 transposed
    mask_conv_kernel<<<(n + 255) / 256, 256, 0, stream>>>(mask, mbuf, n);
    wconv_kernel<<<512, KPAD, 0, stream>>>(W_iou, W_f, Wb_t);

    // 1. input GEMM (MFMA bf16, fused iou_in + f_in + bias + mask)
    {
        dim3 grid(4, (n + 127) / 128);
        gemm_in_mfma<<<grid, 256, 0, stream>>>(x, mbuf, Wb_t, b_iou, b_f,
                                               iou_in, f_in, n);
    }

    // 2. leaves (level 10)
    {
        int start = (pow3[10] - 1) / 2;   // 29524
        int count = pow3[10];             // 59049
        int total = count * 32;
        leaf_kernel<<<(total + 255) / 256, 256, 0, stream>>>(iou_in, hbuf, cbuf,
                                                             start, count);
    }

    // 3. internal levels 9..0
    for (int lvl = 9; lvl >= 0; --lvl) {
        int NP = pow3[lvl];
        int P0 = (pow3[lvl] - 1) / 2;
        int grid = (NP + G - 1) / G;
        level_kernel<<<grid, 128, 0, stream>>>(iou_in, f_in, U_iou, U_f,
                                               hbuf, cbuf, P0, NP);
    }

    // 4. output head
    {
        int blocks = (n + 3) / 4;
        out_kernel<<<blocks, 256, 0, stream>>>(hbuf, W_out, b_out, out, n);
    }
}